// Round 17
// baseline (487.356 us; speedup 1.0000x reference)
//
#include <hip/hip_runtime.h>

// FPS, 2 dispatches, ZERO cross-block communication.
// B=64, N=262144, NPOINT=10.
// scan1 (256x64 blocks): dense pass vs point 0 -> per-record state in global:
//   ub (record max), cd (dmin of candidate), ui (candidate idx), coords.
//   Records: 1024/batch x 256 pts (fine granularity -> tight UBs; R9's 590us
//   came from 4096-pt records: 16KB/survivor + gathered refresh).
// fps_steps (64 blocks, 1 per batch, 1024 thr): loads records into LDS once;
//   all 9 argmax steps in-block (__syncthreads only). Per step: register
//   refresh of cd vs newest center (coords in LDS -> no gather), LB = block
//   argmax of cd (realized value => valid lower bound), survivors =
//   records with staleUB >= LB (strict < prunes; stale ub is monotone-high
//   => never drops the winner; pruned records are strictly below the winner
//   so they can never tie), wave-parallel exact rescans, winner = packed
//   (val desc, idx asc) reduce -> matches jnp.argmax first-occurrence.
//   All fminf folds in reference association order -> bit-exact.

#define NPOINT 10
#define NB     64
#define NPTS   262144
#define NR     1024          // records per batch
#define HCH    256           // points per record
#define TPA    256           // scan1 block (4 waves -> 4 records)
#define TPB    1024          // steps block (16 waves)
#define INIT_DIST 1e10f

// Strict IEEE, reference association order ((dx^2+dy^2)+dz^2), no contraction.
__device__ __forceinline__ float sqdist(float x, float y, float z,
                                        float cx, float cy, float cz) {
    float dx = x - cx, dy = y - cy, dz = z - cz;
    return __fadd_rn(__fadd_rn(__fmul_rn(dx, dx), __fmul_rn(dy, dy)),
                     __fmul_rn(dz, dz));
}

// 64-lane shfl argmax (max val, ties -> lowest idx); result in lane 0.
__device__ __forceinline__ void wave_argmax(float& v, int& i) {
    #pragma unroll
    for (int off = 32; off > 0; off >>= 1) {
        float ov = __shfl_down(v, off); int oi = __shfl_down(i, off);
        if (ov > v || (ov == v && oi < i)) { v = ov; i = oi; }
    }
}

// Wave scan of record rec (256 pts, 4/lane, ascending) vs centers 0..R-1;
// result in lane 0, lowest-idx ties.
template <int R>
__device__ __forceinline__ void scanW(const float* __restrict__ xyzb, int rec,
                                      int lane, const float* scx,
                                      const float* scy, const float* scz,
                                      float& outv, int& outi) {
    float cx[R], cy[R], cz[R];
    #pragma unroll
    for (int k = 0; k < R; ++k) { cx[k] = scx[k]; cy[k] = scy[k]; cz[k] = scz[k]; }
    const int p0 = rec * HCH + lane * 4;
    const float4* src = (const float4*)(xyzb + (size_t)p0 * 3);
    float4 a = src[0], m4 = src[1], e = src[2];
    float X[4] = {a.x, a.w, m4.z, e.y};
    float Y[4] = {a.y, m4.x, m4.w, e.z};
    float Z[4] = {a.z, m4.y, e.x, e.w};
    float bv = -1.0f; int bi = 0;
    #pragma unroll
    for (int j = 0; j < 4; ++j) {
        float dmin = INIT_DIST;
        #pragma unroll
        for (int k = 0; k < R; ++k)
            dmin = fminf(dmin, sqdist(X[j], Y[j], Z[j], cx[k], cy[k], cz[k]));
        if (dmin > bv) { bv = dmin; bi = p0 + j; }
    }
    wave_argmax(bv, bi);
    outv = bv; outi = bi;
}

// ---- scan1: dense pass vs point 0 -> full record state (rewritten every
//      call -> replay-safe).
__global__ __launch_bounds__(TPA) void fps_scan1(
    const float* __restrict__ xyz,
    float* __restrict__ ub, float* __restrict__ cd, int* __restrict__ ui,
    float* __restrict__ px, float* __restrict__ py, float* __restrict__ pz)
{
    const int g = blockIdx.x, b = blockIdx.y, tid = threadIdx.x;
    const int lane = tid & 63, wv = tid >> 6;
    const float* xyzb = xyz + (size_t)b * NPTS * 3;
    const float ax[1] = {xyzb[0]}, ay[1] = {xyzb[1]}, az[1] = {xyzb[2]};
    const int rec = g * 4 + wv;
    float v; int i;
    scanW<1>(xyzb, rec, lane, ax, ay, az, v, i);
    if (lane == 0) {
        const int o = b * NR + rec;
        ub[o] = v; cd[o] = v; ui[o] = i;
        const float* qq = xyzb + (size_t)i * 3;
        px[o] = qq[0]; py[o] = qq[1]; pz[o] = qq[2];
    }
}

// ---- one FPS step entirely in-block: centers 0..K-1, produces out[K].
template <int K>
__device__ __forceinline__ void one_step(
    const float* __restrict__ xyzb, int b, int tid, int lane, int wv,
    float* l_ub, float* l_cd, int* l_ui,
    float* l_px, float* l_py, float* l_pz,
    float* scx, float* scy, float* scz,
    float* s_pv, int* s_pi, int* s_cnt, int* s_pre, int* s_sl,
    int* s_M, float* s_lb, int* __restrict__ out)
{
    // refresh my record's cand vs newest center K-1 (register math, no gather)
    float cd2 = fminf(l_cd[tid], sqdist(l_px[tid], l_py[tid], l_pz[tid],
                                        scx[K - 1], scy[K - 1], scz[K - 1]));
    l_cd[tid] = cd2;

    // LB = max refreshed cand (realized value)
    float m = cd2;
    #pragma unroll
    for (int off = 32; off > 0; off >>= 1) m = fmaxf(m, __shfl_down(m, off));
    if (lane == 0) s_pv[wv] = m;
    __syncthreads();
    if (tid == 0) {
        float mm = s_pv[0];
        #pragma unroll
        for (int w = 1; w < 16; ++w) mm = fmaxf(mm, s_pv[w]);
        *s_lb = mm;
    }
    __syncthreads();
    const float LB = *s_lb;

    // survivor compaction (strict <: value-ties stay scannable)
    const bool flag = (l_ub[tid] >= LB);
    const unsigned long long bm = __ballot(flag);
    if (lane == 0) s_cnt[wv] = (int)__popcll(bm);
    __syncthreads();
    if (tid == 0) {
        int acc = 0;
        #pragma unroll
        for (int w = 0; w < 16; ++w) { s_pre[w] = acc; acc += s_cnt[w]; }
        *s_M = acc;
    }
    __syncthreads();
    if (flag) {
        int pos = s_pre[wv] + (int)__popcll(bm & ((1ull << lane) - 1ull));
        s_sl[pos] = tid;
    }
    __syncthreads();
    const int M = *s_M;

    // wave-parallel exact rescans; track step winner among scanned records
    float bv = -1.0f; int bi = 0x7fffffff;
    for (int t = wv; t < M; t += 16) {
        const int rec = s_sl[t];
        float v; int i;
        scanW<K>(xyzb, rec, lane, scx, scy, scz, v, i);
        if (lane == 0) {
            l_ub[rec] = v; l_cd[rec] = v; l_ui[rec] = i;
            const float* qq = xyzb + (size_t)i * 3;
            l_px[rec] = qq[0]; l_py[rec] = qq[1]; l_pz[rec] = qq[2];
            if (v > bv || (v == bv && i < bi)) { bv = v; bi = i; }
        }
    }
    if (lane == 0) { s_pv[wv] = bv; s_pi[wv] = bi; }
    __syncthreads();
    if (tid == 0) {
        float v2 = s_pv[0]; int i2 = s_pi[0];
        #pragma unroll
        for (int w = 1; w < 16; ++w)
            if (s_pv[w] > v2 || (s_pv[w] == v2 && s_pi[w] < i2)) {
                v2 = s_pv[w]; i2 = s_pi[w];
            }
        out[b * NPOINT + K] = i2;
        const float* pp = xyzb + (size_t)i2 * 3;
        scx[K] = pp[0]; scy[K] = pp[1]; scz[K] = pp[2];
    }
    __syncthreads();
}

// ---- fps_steps: one block per batch, all steps, no cross-block comm.
__global__ __launch_bounds__(TPB, 1) void fps_steps(
    const float* __restrict__ xyz,
    const float* __restrict__ ub_g, const float* __restrict__ cd_g,
    const int* __restrict__ ui_g, const float* __restrict__ px_g,
    const float* __restrict__ py_g, const float* __restrict__ pz_g,
    int* __restrict__ out)
{
    const int b = blockIdx.x, tid = threadIdx.x;
    const int lane = tid & 63, wv = tid >> 6;
    const float* xyzb = xyz + (size_t)b * NPTS * 3;
    const int boff = b * NR;

    __shared__ float l_ub[NR], l_cd[NR], l_px[NR], l_py[NR], l_pz[NR];
    __shared__ int   l_ui[NR];
    __shared__ float scx[NPOINT + 1], scy[NPOINT + 1], scz[NPOINT + 1];
    __shared__ float s_pv[16]; __shared__ int s_pi[16];
    __shared__ int   s_cnt[16], s_pre[16], s_sl[NR], s_M;
    __shared__ float s_lb;

    // load records (contiguous, written by scan1 in the previous dispatch)
    l_ub[tid] = ub_g[boff + tid]; l_cd[tid] = cd_g[boff + tid];
    l_ui[tid] = ui_g[boff + tid];
    l_px[tid] = px_g[boff + tid]; l_py[tid] = py_g[boff + tid];
    l_pz[tid] = pz_g[boff + tid];
    if (tid == 0) { scx[0] = xyzb[0]; scy[0] = xyzb[1]; scz[0] = xyzb[2]; }
    __syncthreads();

    // step 1: argmax over fresh records (max ub, lowest ui ties)
    {
        float v = l_ub[tid]; int i = l_ui[tid];
        wave_argmax(v, i);
        if (lane == 0) { s_pv[wv] = v; s_pi[wv] = i; }
        __syncthreads();
        if (tid == 0) {
            float v2 = s_pv[0]; int i2 = s_pi[0];
            #pragma unroll
            for (int w = 1; w < 16; ++w)
                if (s_pv[w] > v2 || (s_pv[w] == v2 && s_pi[w] < i2)) {
                    v2 = s_pv[w]; i2 = s_pi[w];
                }
            out[b * NPOINT + 0] = 0;
            out[b * NPOINT + 1] = i2;
            const float* pp = xyzb + (size_t)i2 * 3;
            scx[1] = pp[0]; scy[1] = pp[1]; scz[1] = pp[2];
        }
        __syncthreads();
    }

    one_step<2>(xyzb, b, tid, lane, wv, l_ub, l_cd, l_ui, l_px, l_py, l_pz,
                scx, scy, scz, s_pv, s_pi, s_cnt, s_pre, s_sl, &s_M, &s_lb, out);
    one_step<3>(xyzb, b, tid, lane, wv, l_ub, l_cd, l_ui, l_px, l_py, l_pz,
                scx, scy, scz, s_pv, s_pi, s_cnt, s_pre, s_sl, &s_M, &s_lb, out);
    one_step<4>(xyzb, b, tid, lane, wv, l_ub, l_cd, l_ui, l_px, l_py, l_pz,
                scx, scy, scz, s_pv, s_pi, s_cnt, s_pre, s_sl, &s_M, &s_lb, out);
    one_step<5>(xyzb, b, tid, lane, wv, l_ub, l_cd, l_ui, l_px, l_py, l_pz,
                scx, scy, scz, s_pv, s_pi, s_cnt, s_pre, s_sl, &s_M, &s_lb, out);
    one_step<6>(xyzb, b, tid, lane, wv, l_ub, l_cd, l_ui, l_px, l_py, l_pz,
                scx, scy, scz, s_pv, s_pi, s_cnt, s_pre, s_sl, &s_M, &s_lb, out);
    one_step<7>(xyzb, b, tid, lane, wv, l_ub, l_cd, l_ui, l_px, l_py, l_pz,
                scx, scy, scz, s_pv, s_pi, s_cnt, s_pre, s_sl, &s_M, &s_lb, out);
    one_step<8>(xyzb, b, tid, lane, wv, l_ub, l_cd, l_ui, l_px, l_py, l_pz,
                scx, scy, scz, s_pv, s_pi, s_cnt, s_pre, s_sl, &s_M, &s_lb, out);
    one_step<9>(xyzb, b, tid, lane, wv, l_ub, l_cd, l_ui, l_px, l_py, l_pz,
                scx, scy, scz, s_pv, s_pi, s_cnt, s_pre, s_sl, &s_M, &s_lb, out);
}

extern "C" void kernel_launch(void* const* d_in, const int* in_sizes, int n_in,
                              void* d_out, int out_size, void* d_ws, size_t ws_size,
                              hipStream_t stream) {
    const float* xyz = (const float*)d_in[0];
    int* out = (int*)d_out;
    char* ws = (char*)d_ws;

    float* ub = (float*)(ws + 0);                       // 256 KB each
    float* cd = (float*)(ws + (size_t)256 * 1024);
    int*   ui = (int*)  (ws + (size_t)512 * 1024);
    float* px = (float*)(ws + (size_t)768 * 1024);
    float* py = (float*)(ws + (size_t)1024 * 1024);
    float* pz = (float*)(ws + (size_t)1280 * 1024);

    fps_scan1<<<dim3(NR / 4, NB), dim3(TPA), 0, stream>>>(xyz, ub, cd, ui,
                                                          px, py, pz);
    fps_steps<<<dim3(NB), dim3(TPB), 0, stream>>>(xyz, ub, cd, ui,
                                                  px, py, pz, out);
}

// Round 18
// 288.757 us; speedup vs baseline: 1.6878x; 1.6878x over previous
//
#include <hip/hip_runtime.h>

// FPS, 9 dispatches (R10 structure minus memset and final).
// B=64, N=262144, NPOINT=10. Records: 256/batch x 1024 pts (quarters):
//   ub (stale max), cd (exact dmin of cand pt), ui, cand-point coords.
// scan1: dense pass vs point 0 -> fresh records; zeroes win slots 2..8
//   (scan1 never posts -> no race); writes out[0], sel[0].
// step<R> (R=2..8, 64x64 blocks x 256 thr): thread-per-record gather-free
//   cand refresh -> LB = max refreshed cand (realized => valid); block's 4
//   owned quarters: pruned (staleUB < LB, strict) -> pass-through from
//   registers; survivors -> exact rescan, full record update, post packed
//   (valbits<<32)|(~idx) atomicMax to win[R]. R==2 resolves the step-1
//   winner via in-block reduce of the loaded records (no win[1], no memset).
// tail (64 blocks x 1024 thr): resolves step-8 winner from win[8] (stable),
//   writes out[8]; runs step 9 entirely in-block (refresh, LB, 16-wave
//   survivor scans), writes out[9]. No cross-block plain-memory handoffs
//   anywhere inside a kernel (R14-16 lesson).

#define NPOINT 10
#define NB     64
#define NPTS   262144
#define QN     256          // quarters per batch
#define QCH    1024         // points per quarter
#define TPB    256
#define GB     64           // step-kernel blocks per batch (4 quarters each)
#define INIT_DIST 1e10f

// Strict IEEE, reference association order ((dx^2+dy^2)+dz^2), no contraction.
__device__ __forceinline__ float sqdist(float x, float y, float z,
                                        float cx, float cy, float cz) {
    float dx = x - cx, dy = y - cy, dz = z - cz;
    return __fadd_rn(__fadd_rn(__fmul_rn(dx, dx), __fmul_rn(dy, dy)),
                     __fmul_rn(dz, dz));
}

__device__ __forceinline__ unsigned long long packvi(float v, int i) {
    return ((unsigned long long)__float_as_uint(v) << 32) |
           (unsigned)(0xFFFFFFFFu - (unsigned)i);
}
__device__ __forceinline__ int unpack_idx(unsigned long long w) {
    return (int)(0xFFFFFFFFu - (unsigned)(w & 0xFFFFFFFFull));
}

// 64-lane shfl argmax (max val, ties -> lowest idx); result in lane 0.
__device__ __forceinline__ void wave_argmax(float& v, int& i) {
    #pragma unroll
    for (int off = 32; off > 0; off >>= 1) {
        float ov = __shfl_down(v, off); int oi = __shfl_down(i, off);
        if (ov > v || (ov == v && oi < i)) { v = ov; i = oi; }
    }
}

// ---- Kernel A: full scan vs point 0 -> fresh quarter records.
__global__ __launch_bounds__(TPB) void fps_scan1(
    const float* __restrict__ xyz, int* __restrict__ out,
    float4* __restrict__ sel,
    float* __restrict__ ub, float* __restrict__ cd, int* __restrict__ ui,
    float* __restrict__ px, float* __restrict__ py, float* __restrict__ pz,
    unsigned long long* __restrict__ win)
{
    const int c = blockIdx.x, b = blockIdx.y, tid = threadIdx.x;
    const int lane = tid & 63, wv = tid >> 6;
    const float* xyzb = xyz + (size_t)b * NPTS * 3;
    const float c0x = xyzb[0], c0y = xyzb[1], c0z = xyzb[2];
    __shared__ float s_v[4];
    __shared__ int   s_i[4];

    if (c == 0 && tid >= 2 && tid <= 8)       // zero win slots 2..8 (no race:
        win[((size_t)tid * NB + b) * 16] = 0ULL;  // scan1 never posts)

    const int p0 = c * QCH + tid * 4;
    const float4* src = (const float4*)(xyzb + (size_t)p0 * 3);
    float4 a = src[0], m = src[1], e = src[2];
    float X[4] = {a.x, a.w, m.z, e.y};
    float Y[4] = {a.y, m.x, m.w, e.z};
    float Z[4] = {a.z, m.y, e.x, e.w};
    float bv = -1.0f; int bi = 0;
    #pragma unroll
    for (int j = 0; j < 4; ++j) {
        float d = fminf(INIT_DIST, sqdist(X[j], Y[j], Z[j], c0x, c0y, c0z));
        if (d > bv) { bv = d; bi = p0 + j; }
    }
    wave_argmax(bv, bi);
    if (lane == 0) { s_v[wv] = bv; s_i[wv] = bi; }
    __syncthreads();
    if (tid == 0) {
        float v = s_v[0]; int i = s_i[0];
        #pragma unroll
        for (int w = 1; w < 4; ++w) {
            float ov = s_v[w]; int oi = s_i[w];
            if (ov > v || (ov == v && oi < i)) { v = ov; i = oi; }
        }
        const int o = b * QN + c;
        ub[o] = v; cd[o] = v; ui[o] = i;
        const float* qq = xyzb + (size_t)i * 3;
        px[o] = qq[0]; py[o] = qq[1]; pz[o] = qq[2];
        if (c == 0) {
            out[b * NPOINT + 0] = 0;
            sel[b * NPOINT + 0] = make_float4(c0x, c0y, c0z, 0.f);
        }
    }
}

// ---- Kernel B: one FPS step. Block g owns quarters 4g..4g+3.
template <int R>
__global__ __launch_bounds__(TPB) void fps_step(
    const float* __restrict__ xyz, int* __restrict__ out,
    float4* __restrict__ sel,
    const float* __restrict__ ub_i, const float* __restrict__ cd_i,
    const int* __restrict__ ui_i, const float* __restrict__ px_i,
    const float* __restrict__ py_i, const float* __restrict__ pz_i,
    float* __restrict__ ub_o, float* __restrict__ cd_o, int* __restrict__ ui_o,
    float* __restrict__ px_o, float* __restrict__ py_o, float* __restrict__ pz_o,
    unsigned long long* __restrict__ win)
{
    const int g = blockIdx.x, b = blockIdx.y, tid = threadIdx.x;
    const int lane = tid & 63, wv = tid >> 6;
    const float* xyzb = xyz + (size_t)b * NPTS * 3;
    const int boff = b * QN;

    __shared__ float scx[NPOINT], scy[NPOINT], scz[NPOINT];
    __shared__ float s_r[4], s_qub[4];
    __shared__ float s_v[4];
    __shared__ int   s_i[4];
    __shared__ int   s_prev;

    // thread tid owns record tid (contiguous loads, stable prev-dispatch data)
    float myub = ub_i[boff + tid];
    float mycd = cd_i[boff + tid];
    int   myui = ui_i[boff + tid];
    float mx = px_i[boff + tid], my = py_i[boff + tid], mz = pz_i[boff + tid];

    // resolve winner of step R-1
    int prevIdx;
    if constexpr (R == 2) {
        // deterministic in-block reduce over fresh records (no win[1] needed)
        float v = myub; int i = myui;
        wave_argmax(v, i);
        if (lane == 0) { s_v[wv] = v; s_i[wv] = i; }
        __syncthreads();
        if (tid == 0) {
            float v2 = s_v[0]; int i2 = s_i[0];
            #pragma unroll
            for (int w = 1; w < 4; ++w)
                if (s_v[w] > v2 || (s_v[w] == v2 && s_i[w] < i2)) {
                    v2 = s_v[w]; i2 = s_i[w];
                }
            s_prev = i2;
        }
        __syncthreads();
        prevIdx = s_prev;
    } else {
        prevIdx = unpack_idx(win[((size_t)(R - 1) * NB + b) * 16]);
    }
    const float* pp = xyzb + (size_t)prevIdx * 3;
    const float pcx = pp[0], pcy = pp[1], pcz = pp[2];

    if (tid < R - 1) {
        float4 q = sel[b * NPOINT + tid];
        scx[tid] = q.x; scy[tid] = q.y; scz[tid] = q.z;
    }
    if (tid == 0) { scx[R - 1] = pcx; scy[R - 1] = pcy; scz[R - 1] = pcz; }

    // gather-free cand refresh
    mycd = fminf(mycd, sqdist(mx, my, mz, pcx, pcy, pcz));

    // LB = max refreshed cand (value-only block reduce)
    float rv = mycd;
    #pragma unroll
    for (int off = 32; off > 0; off >>= 1)
        rv = fmaxf(rv, __shfl_down(rv, off));
    if (lane == 0) s_r[wv] = rv;
    const int dq = tid - 4 * g;                 // this block's 4 quarter ubs
    if (dq >= 0 && dq < 4) s_qub[dq] = myub;
    __syncthreads();
    const float LB = fmaxf(fmaxf(s_r[0], s_r[1]), fmaxf(s_r[2], s_r[3]));

    if (g == 0 && tid == 0) {                   // bookkeeping (next dispatches)
        out[b * NPOINT + (R - 1)] = prevIdx;
        sel[b * NPOINT + (R - 1)] = make_float4(pcx, pcy, pcz, 0.f);
    }

    // pass-through for pruned quarters (owner thread has the record in regs)
    const bool mine = (dq >= 0 && dq < 4);
    const bool my_survives = mine && (myub >= LB);
    if (mine && !my_survives) {
        ub_o[boff + tid] = myub; cd_o[boff + tid] = mycd; ui_o[boff + tid] = myui;
        px_o[boff + tid] = mx;   py_o[boff + tid] = my;   pz_o[boff + tid] = mz;
    }

    unsigned long long* const wr = win + ((size_t)R * NB + b) * 16;
    #pragma unroll
    for (int j = 0; j < 4; ++j) {
        if (s_qub[j] < LB) continue;            // strict: ties stay scannable
        const int q = 4 * g + j;
        const int p0 = q * QCH + tid * 4;
        const float4* src = (const float4*)(xyzb + (size_t)p0 * 3);
        float4 a = src[0], m4 = src[1], e = src[2];
        float X[4] = {a.x, a.w, m4.z, e.y};
        float Y[4] = {a.y, m4.x, m4.w, e.z};
        float Z[4] = {a.z, m4.y, e.x, e.w};
        float bv = -1.0f; int bi = 0;
        #pragma unroll
        for (int t = 0; t < 4; ++t) {
            float dmin = INIT_DIST;
            #pragma unroll
            for (int k = 0; k < R; ++k)
                dmin = fminf(dmin, sqdist(X[t], Y[t], Z[t], scx[k], scy[k], scz[k]));
            if (dmin > bv) { bv = dmin; bi = p0 + t; }
        }
        wave_argmax(bv, bi);
        if (lane == 0) { s_v[wv] = bv; s_i[wv] = bi; }
        __syncthreads();
        if (tid == 0) {
            float v = s_v[0]; int i = s_i[0];
            #pragma unroll
            for (int u = 1; u < 4; ++u) {
                float ov = s_v[u]; int oi = s_i[u];
                if (ov > v || (ov == v && oi < i)) { v = ov; i = oi; }
            }
            const float* qq = xyzb + (size_t)i * 3;
            ub_o[boff + q] = v; cd_o[boff + q] = v; ui_o[boff + q] = i;
            px_o[boff + q] = qq[0]; py_o[boff + q] = qq[1]; pz_o[boff + q] = qq[2];
            atomicMax(wr, packvi(v, i));
        }
        __syncthreads();
    }
}

// Wave-level exact scan of quarter q (1024 pts, 16/lane) vs centers 0..R-1.
template <int R>
__device__ __forceinline__ void scanQ(const float* __restrict__ xyzb, int q,
                                      int lane, const float* scx,
                                      const float* scy, const float* scz,
                                      float& outv, int& outi) {
    float cx[R], cy[R], cz[R];
    #pragma unroll
    for (int k = 0; k < R; ++k) { cx[k] = scx[k]; cy[k] = scy[k]; cz[k] = scz[k]; }
    float bestv = -1.0f; int besti = 0;
    const int p0 = q * QCH + lane * 16;
    #pragma unroll
    for (int grp = 0; grp < 4; ++grp) {
        const float4* src = (const float4*)(xyzb + (size_t)(p0 + grp * 4) * 3);
        float4 a = src[0], m4 = src[1], e = src[2];
        float X[4] = {a.x, a.w, m4.z, e.y};
        float Y[4] = {a.y, m4.x, m4.w, e.z};
        float Z[4] = {a.z, m4.y, e.x, e.w};
        #pragma unroll
        for (int j = 0; j < 4; ++j) {
            float dmin = INIT_DIST;
            #pragma unroll
            for (int k = 0; k < R; ++k)
                dmin = fminf(dmin, sqdist(X[j], Y[j], Z[j], cx[k], cy[k], cz[k]));
            if (dmin > bestv) { bestv = dmin; besti = p0 + grp * 4 + j; }
        }
    }
    wave_argmax(bestv, besti);
    outv = bestv; outi = besti;
}

// ---- Kernel C: tail = resolve step-8 winner + full step 9 in-block.
__global__ __launch_bounds__(1024, 1) void fps_tail(
    const float* __restrict__ xyz, int* __restrict__ out,
    const float4* __restrict__ sel,
    const float* __restrict__ ub_i, const float* __restrict__ cd_i,
    const float* __restrict__ px_i, const float* __restrict__ py_i,
    const float* __restrict__ pz_i,
    const unsigned long long* __restrict__ win)
{
    const int b = blockIdx.x, tid = threadIdx.x;
    const int lane = tid & 63, wv = tid >> 6;
    const float* xyzb = xyz + (size_t)b * NPTS * 3;
    const int boff = b * QN;

    __shared__ float scx[9], scy[9], scz[9];
    __shared__ float s_v[16]; __shared__ int s_i[16];
    __shared__ int   s_cnt[16], s_pre[16], s_sl[QN], s_M;
    __shared__ float s_lb;

    if (tid < 8) {                              // centers 0..7 (stable sel)
        float4 q = sel[b * NPOINT + tid];
        scx[tid] = q.x; scy[tid] = q.y; scz[tid] = q.z;
    }
    if (tid == 0) {                             // center 8 = step-8 winner
        const int prevIdx = unpack_idx(win[((size_t)8 * NB + b) * 16]);
        out[b * NPOINT + 8] = prevIdx;
        const float* pp = xyzb + (size_t)prevIdx * 3;
        scx[8] = pp[0]; scy[8] = pp[1]; scz[8] = pp[2];
    }
    __syncthreads();

    // refresh cands (thread-per-record for tid<256), LB
    float myub = -1.0f, mycd = -1.0f;
    if (tid < QN) {
        myub = ub_i[boff + tid];
        mycd = fminf(cd_i[boff + tid],
                     sqdist(px_i[boff + tid], py_i[boff + tid],
                            pz_i[boff + tid], scx[8], scy[8], scz[8]));
    }
    float m = mycd;
    #pragma unroll
    for (int off = 32; off > 0; off >>= 1) m = fmaxf(m, __shfl_down(m, off));
    if (lane == 0) s_v[wv] = m;
    __syncthreads();
    if (tid == 0) {
        float mm = s_v[0];
        #pragma unroll
        for (int w = 1; w < 16; ++w) mm = fmaxf(mm, s_v[w]);
        s_lb = mm;
    }
    __syncthreads();
    const float LB = s_lb;

    // survivor compaction
    const bool flag = (tid < QN) && (myub >= LB);
    const unsigned long long bm = __ballot(flag);
    if (lane == 0) s_cnt[wv] = (int)__popcll(bm);
    __syncthreads();
    if (tid == 0) {
        int acc = 0;
        #pragma unroll
        for (int w = 0; w < 16; ++w) { s_pre[w] = acc; acc += s_cnt[w]; }
        s_M = acc;
    }
    __syncthreads();
    if (flag) {
        int pos = s_pre[wv] + (int)__popcll(bm & ((1ull << lane) - 1ull));
        s_sl[pos] = tid;
    }
    __syncthreads();
    const int M = s_M;

    // 16-wave survivor scans; winner = (max val, lowest idx)
    float bv = -1.0f; int bi = 0x7fffffff;
    for (int t = wv; t < M; t += 16) {
        float v; int i;
        scanQ<9>(xyzb, s_sl[t], lane, scx, scy, scz, v, i);
        if (lane == 0 && (v > bv || (v == bv && i < bi))) { bv = v; bi = i; }
    }
    if (lane == 0) { s_v[wv] = bv; s_i[wv] = bi; }
    __syncthreads();
    if (tid == 0) {
        float v2 = s_v[0]; int i2 = s_i[0];
        #pragma unroll
        for (int w = 1; w < 16; ++w)
            if (s_v[w] > v2 || (s_v[w] == v2 && s_i[w] < i2)) {
                v2 = s_v[w]; i2 = s_i[w];
            }
        out[b * NPOINT + 9] = i2;
    }
}

extern "C" void kernel_launch(void* const* d_in, const int* in_sizes, int n_in,
                              void* d_out, int out_size, void* d_ws, size_t ws_size,
                              hipStream_t stream) {
    const float* xyz = (const float*)d_in[0];
    int* out = (int*)d_out;
    char* ws = (char*)d_ws;

    float* ub0 = (float*)(ws + 0);       float* ub1 = (float*)(ws + 65536);
    float* cd0 = (float*)(ws + 131072);  float* cd1 = (float*)(ws + 196608);
    int*   ui0 = (int*)  (ws + 262144);  int*   ui1 = (int*)  (ws + 327680);
    float* px0 = (float*)(ws + 393216);  float* px1 = (float*)(ws + 458752);
    float* py0 = (float*)(ws + 524288);  float* py1 = (float*)(ws + 589824);
    float* pz0 = (float*)(ws + 655360);  float* pz1 = (float*)(ws + 720896);
    float4* sel = (float4*)(ws + 786432);                         // 10240 B
    unsigned long long* win = (unsigned long long*)(ws + 798720); // 73728 B

    dim3 gridA(QN, NB), gridB(GB, NB), block(TPB);
    fps_scan1<<<gridA, block, 0, stream>>>(xyz, out, sel, ub0, cd0, ui0,
                                           px0, py0, pz0, win);
    fps_step<2><<<gridB, block, 0, stream>>>(xyz, out, sel, ub0, cd0, ui0, px0, py0, pz0,
                                             ub1, cd1, ui1, px1, py1, pz1, win);
    fps_step<3><<<gridB, block, 0, stream>>>(xyz, out, sel, ub1, cd1, ui1, px1, py1, pz1,
                                             ub0, cd0, ui0, px0, py0, pz0, win);
    fps_step<4><<<gridB, block, 0, stream>>>(xyz, out, sel, ub0, cd0, ui0, px0, py0, pz0,
                                             ub1, cd1, ui1, px1, py1, pz1, win);
    fps_step<5><<<gridB, block, 0, stream>>>(xyz, out, sel, ub1, cd1, ui1, px1, py1, pz1,
                                             ub0, cd0, ui0, px0, py0, pz0, win);
    fps_step<6><<<gridB, block, 0, stream>>>(xyz, out, sel, ub0, cd0, ui0, px0, py0, pz0,
                                             ub1, cd1, ui1, px1, py1, pz1, win);
    fps_step<7><<<gridB, block, 0, stream>>>(xyz, out, sel, ub1, cd1, ui1, px1, py1, pz1,
                                             ub0, cd0, ui0, px0, py0, pz0, win);
    fps_step<8><<<gridB, block, 0, stream>>>(xyz, out, sel, ub0, cd0, ui0, px0, py0, pz0,
                                             ub1, cd1, ui1, px1, py1, pz1, win);
    fps_tail<<<dim3(NB), dim3(1024), 0, stream>>>(xyz, out, sel, ub1, cd1,
                                                  px1, py1, pz1, win);
}